// Round 5
// baseline (24.359 us; speedup 1.0000x reference)
//
#include <hip/hip_runtime.h>
#include <math.h>

#define NB 64

struct C { float x, y; };

__device__ __forceinline__ C cmul(C a, C b){ return C{a.x*b.x - a.y*b.y, a.x*b.y + a.y*b.x}; }

// new_j = sum_i x_i * G[i][j]  (reference einsum contracts gate's FIRST index with state)
__device__ __forceinline__ void bfly(C& x0, C& x1, const C* G){
  C n0 = C{x0.x*G[0].x - x0.y*G[0].y + x1.x*G[2].x - x1.y*G[2].y,
           x0.x*G[0].y + x0.y*G[0].x + x1.x*G[2].y + x1.y*G[2].x};
  C n1 = C{x0.x*G[1].x - x0.y*G[1].y + x1.x*G[3].x - x1.y*G[3].y,
           x0.x*G[1].y + x0.y*G[1].x + x1.x*G[3].y + x1.y*G[3].x};
  x0 = n0; x1 = n1;
}

// interleave: t2 bits -> even positions, k2 bits -> odd positions
__device__ __forceinline__ int expand44(int t2, int k2){
  int j=0;
  #pragma unroll
  for (int m=0;m<4;m++){ j |= ((t2>>m)&1)<<(2*m); j |= ((k2>>m)&1)<<(2*m+1); }
  return j;
}

// M = Rx(tx)*Ry(ty)*Rz(tz), row-major M[i*2+j]; reference applies new = x^T * M
__device__ void fused_M(float tx, float ty, float tz, C* M){
  float cx=cosf(0.5f*tx), sx=sinf(0.5f*tx);
  float cy=cosf(0.5f*ty), sy=sinf(0.5f*ty);
  float cz=cosf(0.5f*tz), sz=sinf(0.5f*tz);
  C b0 = C{ cx*cy, -sx*sy};
  C b1 = C{-cx*sy, -sx*cy};
  C b2 = C{ cx*sy, -sx*cy};
  C b3 = C{ cx*cy,  sx*sy};
  C e0 = C{cz,-sz}, e1 = C{cz, sz};
  M[0]=cmul(b0,e0); M[1]=cmul(b1,e1);
  M[2]=cmul(b2,e0); M[3]=cmul(b3,e1);
}

// ============ SINGLE-WAVE-PER-BATCH KERNEL: rank-2 factored simulation ============
// Block = 64 threads = 1 wave. With __launch_bounds__(64) the backend lowers
// s_barrier to a no-op (workgroup fits one wave), so every __syncthreads() below
// is just a waitcnt — the whole kernel runs barrier-free.
__global__ __launch_bounds__(64) void k_all(
    const float* __restrict__ nbr, const float* __restrict__ slf,
    const float* __restrict__ Wp, const float* __restrict__ bp,
    const float* __restrict__ rot0, const float* __restrict__ zz0,
    const float* __restrict__ rot1, const float* __restrict__ zz1,
    const float* __restrict__ Wo, const float* __restrict__ bo,
    float* __restrict__ out)
{
  const int b = blockIdx.x, tid = threadIdx.x;

  __shared__ float thp[48][4];
  __shared__ float th[48];
  __shared__ C vq[16][2];
  __shared__ float zz0s[15];
  __shared__ C M0s[16][4];
  __shared__ C lam[2];
  __shared__ C W[4][256];               // A0, A1, B0, B1
  __shared__ float GH00[16], GH11[16], GL00[16], GL11[16];
  __shared__ C GH01[16], GL01[16];
  __shared__ float w[256];
  __shared__ C Mx[2][16][16];
  __shared__ C s8[256];
  __shared__ C M1s[8][4];
  __shared__ float zz1s[7];

  // ---- prefetch head weights (used only at the very end) ----
  float4 wo4 = ((const float4*)Wo)[tid];
  float bor  = bo[tid];

  // ---- prep: gate matrices + small params, distributed across the wave ----
  if (tid >= 32 && tid < 47) zz0s[tid-32] = zz0[tid-32];
  if (tid < 16){
    fused_M(rot0[tid*3+0], rot0[tid*3+1], rot0[tid*3+2], &M0s[tid][0]);
  } else if (tid < 24){
    int q = tid-16;
    fused_M(rot1[q*3+0], rot1[q*3+1], rot1[q*3+2], &M1s[q][0]);
  } else if (tid < 31){
    zz1s[tid-24] = zz1[tid-24];
  } else if (tid == 31){
    // boundary ZZ pair rank-2 split: [[a,b],[b,a]] = c*(1x1) + (-i s)*(sgn x sgn)
    float s,c; sincosf(0.5f*zz0[7],&s,&c);
    lam[0] = C{c,0.f}; lam[1] = C{0.f,-s};
  }

  // ---- angle GEMM partials: 192 slots over 64 lanes ----
  for (int s = tid; s < 192; s += 64){
    int o = s>>2, prt = s&3;
    int g = o/12, j = o - g*12;
    const float* f = (g==0) ? (slf + (size_t)b*128) : (nbr + ((size_t)b*3 + (g-1))*128);
    const float4* f4 = (const float4*)(f + prt*32);
    const float4* w4 = (const float4*)(Wp + j*128 + prt*32);
    float acc = 0.f;
    #pragma unroll
    for (int d=0; d<8; d++){
      float4 a = f4[d], c = w4[d];
      acc += a.x*c.x + a.y*c.y + a.z*c.z + a.w*c.w;
    }
    thp[o][prt] = acc;
  }
  __syncthreads();
  if (tid < 48) th[tid] = thp[tid][0]+thp[tid][1]+thp[tid][2]+thp[tid][3] + bp[tid%12];
  __syncthreads();
  if (tid < 16){
    C M[4]; fused_M(th[tid*3+0], th[tid*3+1], th[tid*3+2], M);
    vq[tid][0] = M[0]; vq[tid][1] = M[1];   // row 0 of e0^T * RxRyRz (encoding on |0>)
  }
  __syncthreads();

  // ---- byte-function init: Vh/Vl -> A0,A1,B0,B1 (4 entries per lane) ----
  #pragma unroll
  for (int rep=0; rep<4; ++rep){
    int h = tid + rep*64;
    C p = vq[0][(h>>7)&1];
    #pragma unroll
    for (int q=1;q<8;q++) p = cmul(p, vq[q][(h>>(7-q))&1]);
    float A = 0.f;
    #pragma unroll
    for (int kk=0;kk<7;kk++){
      int b0=(h>>(7-kk))&1, b1=(h>>(6-kk))&1;
      A += (b0==b1) ? zz0s[kk] : -zz0s[kk];
    }
    float s,c; sincosf(0.5f*A,&s,&c);
    C Vh = cmul(p, C{c,-s});
    C pl = vq[8][(h>>7)&1];
    #pragma unroll
    for (int q=9;q<16;q++) pl = cmul(pl, vq[q][(h>>(15-q))&1]);
    float Al = 0.f;
    #pragma unroll
    for (int kk=8;kk<15;kk++){
      int b0=(h>>(15-kk))&1, b1=(h>>(14-kk))&1;
      Al += (b0==b1) ? zz0s[kk] : -zz0s[kk];
    }
    sincosf(0.5f*Al,&s,&c);
    C Vl = cmul(pl, C{c,-s});
    W[0][h] = cmul(Vh, lam[0]);
    C a1 = cmul(Vh, lam[1]);
    if (h & 1){ a1.x = -a1.x; a1.y = -a1.y; }
    W[1][h] = a1;
    W[2][h] = Vl;
    W[3][h] = ((h>>7)&1) ? C{-Vl.x,-Vl.y} : Vl;
  }
  __syncthreads();

  // ---- conv0 rotations: 8 butterfly levels, 2 per phase, 4 arrays per lane ----
  // h bit pb <-> qubit 7-pb (M0s[7-pb]); l bit pb <-> qubit 15-pb (M0s[15-pb])
  #pragma unroll
  for (int p=0; p<8; p+=2){
    int mp = 1<<p;
    int x = ((tid>>p)<<(p+2)) | (tid & (mp-1));
    #pragma unroll
    for (int arr=0; arr<4; ++arr){
      const C* Glo = (arr<2) ? &M0s[7-p][0]  : &M0s[15-p][0];
      const C* Ghi = (arr<2) ? &M0s[6-p][0]  : &M0s[14-p][0];
      C c0 = W[arr][x], c1 = W[arr][x|mp], c2 = W[arr][x|(mp<<1)], c3 = W[arr][x|mp|(mp<<1)];
      bfly(c0,c1,Glo); bfly(c2,c3,Glo);
      bfly(c0,c2,Ghi); bfly(c1,c3,Ghi);
      W[arr][x]=c0; W[arr][x|mp]=c1; W[arr][x|(mp<<1)]=c2; W[arr][x|mp|(mp<<1)]=c3;
    }
    __syncthreads();
  }

  // ---- Gram vectors (lanes 0..31) ----
  if (tid < 32){
    int side = tid>>4, tq = tid&15;
    float g00=0.f, g11=0.f; C g01{0.f,0.f};
    #pragma unroll
    for (int kq=0;kq<16;kq++){
      int idx = expand44(tq,kq);
      C a0 = W[side*2+0][idx], a1 = W[side*2+1][idx];
      g00 += a0.x*a0.x + a0.y*a0.y;
      g11 += a1.x*a1.x + a1.y*a1.y;
      g01.x += a0.x*a1.x + a0.y*a1.y;
      g01.y += a0.y*a1.x - a0.x*a1.y;
    }
    if (side==0){ GH00[tq]=g00; GH11[tq]=g11; GH01[tq]=g01; }
    else        { GL00[tq]=g00; GL11[tq]=g11; GL01[tq]=g01; }
  }
  __syncthreads();

  // ---- p(t) (4 per lane), wave-butterfly total, weights ----
  float pv[4]; float vsum = 0.f;
  #pragma unroll
  for (int rep=0; rep<4; ++rep){
    int t = tid + rep*64;
    int tH = t>>4, tL = t&15;
    C gh = GH01[tH], gl = GL01[tL];
    float p_ = GH00[tH]*GL00[tL] + GH11[tH]*GL11[tL] + 2.f*(gh.x*gl.x - gh.y*gl.y);
    p_ = fmaxf(p_, 0.f);
    pv[rep] = p_; vsum += p_;
  }
  #pragma unroll
  for (int off=1; off<64; off<<=1) vsum += __shfl_xor(vsum, off);
  {
    float rtot = vsum + 1e-10f;
    #pragma unroll
    for (int rep=0; rep<4; ++rep) w[tid + rep*64] = sqrtf(pv[rep]/rtot);
  }
  __syncthreads();

  // ---- Mx[r][tH][kL] = sum_tL w(tH,tL) * B_r(tL,kL)  (8 slots per lane) ----
  #pragma unroll
  for (int rep=0; rep<8; ++rep){
    int e = tid + rep*64;
    int r = e>>8, tH = (e>>4)&15, kL = e&15;
    C acc{0.f,0.f};
    #pragma unroll
    for (int tL=0;tL<16;tL++){
      float ww = w[(tH<<4)|tL];
      C bv = W[2+r][expand44(tL,kL)];
      acc.x += ww*bv.x; acc.y += ww*bv.y;
    }
    Mx[r][tH][kL] = acc;
  }
  __syncthreads();

  // ---- s1(k) (4 per lane), wave-butterfly norm, conv1 ZZ phase ----
  C s1v[4]; float nsum = 0.f;
  #pragma unroll
  for (int rep=0; rep<4; ++rep){
    int k = tid + rep*64;
    int kH = k>>4, kL = k&15;
    C s1{0.f,0.f};
    #pragma unroll
    for (int tH=0;tH<16;tH++){
      int ia = expand44(tH,kH);
      C a0 = W[0][ia], m0 = Mx[0][tH][kL];
      C a1 = W[1][ia], m1 = Mx[1][tH][kL];
      s1.x += a0.x*m0.x - a0.y*m0.y + a1.x*m1.x - a1.y*m1.y;
      s1.y += a0.x*m0.y + a0.y*m0.x + a1.x*m1.y + a1.y*m1.x;
    }
    s1v[rep] = s1;
    nsum += s1.x*s1.x + s1.y*s1.y;
  }
  #pragma unroll
  for (int off=1; off<64; off<<=1) nsum += __shfl_xor(nsum, off);
  {
    float n1 = sqrtf(nsum + 1e-10f);
    #pragma unroll
    for (int rep=0; rep<4; ++rep){
      int k = tid + rep*64;
      float A = 0.f;
      #pragma unroll
      for (int kk=0;kk<7;kk++){
        int b0=(k>>(7-kk))&1, b1=(k>>(6-kk))&1;
        A += (b0==b1) ? zz1s[kk] : -zz1s[kk];
      }
      float sa,ca; sincosf(0.5f*A,&sa,&ca);
      C s1n{s1v[rep].x/n1, s1v[rep].y/n1};
      s8[k] = cmul(s1n, C{ca,-sa});
    }
  }
  __syncthreads();

  // ---- conv1: 8 levels, 2 per phase, one 4-group per lane ----
  #pragma unroll
  for (int j=0; j<4; ++j){
    int hb = 7-2*j, lb = 6-2*j;
    int ml = 1<<lb, mh = 1<<hb;
    int x = ((tid>>lb)<<(lb+1)) | (tid & (ml-1));
    x = ((x>>hb)<<(hb+1)) | (x & (mh-1));
    C c0 = s8[x], c1 = s8[x|mh], c2 = s8[x|ml], c3 = s8[x|mh|ml];
    bfly(c0,c1,&M1s[2*j][0]);   bfly(c2,c3,&M1s[2*j][0]);
    bfly(c0,c2,&M1s[2*j+1][0]); bfly(c1,c3,&M1s[2*j+1][0]);
    s8[x]=c0; s8[x|mh]=c1; s8[x|ml]=c2; s8[x|mh|ml]=c3;
    __syncthreads();
  }

  // ---- tail: pool2 + measure + head, registers + shuffles (verified) ----
  {
    int ld = tid & 15;
    float p2v = 0.f;
    #pragma unroll
    for (int k2=0;k2<16;k2++){ C v=s8[expand44(ld,k2)]; p2v += v.x*v.x + v.y*v.y; }
    float S2 = p2v;
    #pragma unroll
    for (int off=1; off<16; off<<=1) S2 += __shfl_xor(S2, off);
    float w2 = sqrtf(p2v/(S2 + 1e-10f));
    C a2{0.f,0.f};
    #pragma unroll
    for (int t2=0;t2<16;t2++){
      float ww = __shfl(w2, t2);          // lanes 0..15 hold valid w2
      C v = s8[expand44(t2, ld)];
      a2.x += v.x*ww; a2.y += v.y*ww;
    }
    float nn = a2.x*a2.x + a2.y*a2.y;
    #pragma unroll
    for (int off=1; off<16; off<<=1) nn += __shfl_xor(nn, off);
    nn += 1e-10f;
    float pr = (a2.x*a2.x + a2.y*a2.y)/nn;   // lane ld represents idx=ld
    float z0=0.f,z1=0.f,z2=0.f,z3=0.f;
    #pragma unroll
    for (int idx=0; idx<16; idx++){
      float p_ = __shfl(pr, idx);
      z0 += ((idx>>3)&1) ? -p_ : p_;
      z1 += ((idx>>2)&1) ? -p_ : p_;
      z2 += ((idx>>1)&1) ? -p_ : p_;
      z3 += ( idx     &1) ? -p_ : p_;
    }
    float r = bor + z0*wo4.x + z1*wo4.y + z2*wo4.z + z3*wo4.w;
    out[(size_t)b*64 + tid] = r;
  }
}

extern "C" void kernel_launch(void* const* d_in, const int* in_sizes, int n_in,
                              void* d_out, int out_size, void* d_ws, size_t ws_size,
                              hipStream_t stream) {
  const float* nbr  = (const float*)d_in[0];
  const float* slf  = (const float*)d_in[1];
  const float* Wp   = (const float*)d_in[2];
  const float* bp   = (const float*)d_in[3];
  const float* rot0 = (const float*)d_in[4];
  const float* zz0  = (const float*)d_in[5];
  const float* rot1 = (const float*)d_in[6];
  const float* zz1  = (const float*)d_in[7];
  const float* Wo   = (const float*)d_in[8];
  const float* bo   = (const float*)d_in[9];
  float* out = (float*)d_out;

  hipLaunchKernelGGL(k_all, dim3(NB), dim3(64), 0, stream,
                     nbr, slf, Wp, bp, rot0, zz0, rot1, zz1, Wo, bo, out);
}

// Round 6
// 18.334 us; speedup vs baseline: 1.3286x; 1.3286x over previous
//
#include <hip/hip_runtime.h>
#include <math.h>

#define NB 64

struct C { float x, y; };

__device__ __forceinline__ C cmul(C a, C b){ return C{a.x*b.x - a.y*b.y, a.x*b.y + a.y*b.x}; }

// new_j = sum_i x_i * G[i][j]  (reference einsum contracts gate's FIRST index with state)
__device__ __forceinline__ void bfly(C& x0, C& x1, const C* G){
  C n0 = C{x0.x*G[0].x - x0.y*G[0].y + x1.x*G[2].x - x1.y*G[2].y,
           x0.x*G[0].y + x0.y*G[0].x + x1.x*G[2].y + x1.y*G[2].x};
  C n1 = C{x0.x*G[1].x - x0.y*G[1].y + x1.x*G[3].x - x1.y*G[3].y,
           x0.x*G[1].y + x0.y*G[1].x + x1.x*G[3].y + x1.y*G[3].x};
  x0 = n0; x1 = n1;
}

// interleave: t2 bits -> even positions, k2 bits -> odd positions
__device__ __forceinline__ int expand44(int t2, int k2){
  int j=0;
  #pragma unroll
  for (int m=0;m<4;m++){ j |= ((t2>>m)&1)<<(2*m); j |= ((k2>>m)&1)<<(2*m+1); }
  return j;
}

// M = Rx(tx)*Ry(ty)*Rz(tz), row-major M[i*2+j]; reference applies new = x^T * M
__device__ void fused_M(float tx, float ty, float tz, C* M){
  float cx=cosf(0.5f*tx), sx=sinf(0.5f*tx);
  float cy=cosf(0.5f*ty), sy=sinf(0.5f*ty);
  float cz=cosf(0.5f*tz), sz=sinf(0.5f*tz);
  C b0 = C{ cx*cy, -sx*sy};
  C b1 = C{-cx*sy, -sx*cy};
  C b2 = C{ cx*sy, -sx*cy};
  C b3 = C{ cx*cy,  sx*sy};
  C e0 = C{cz,-sz}, e1 = C{cz, sz};
  M[0]=cmul(b0,e0); M[1]=cmul(b1,e1);
  M[2]=cmul(b2,e0); M[3]=cmul(b3,e1);
}

// ===== SINGLE KERNEL: rank-2 factored sim; 4 waves; conv0/conv1 in registers =====
__global__ __launch_bounds__(256) void k_all(
    const float* __restrict__ nbr, const float* __restrict__ slf,
    const float* __restrict__ Wp, const float* __restrict__ bp,
    const float* __restrict__ rot0, const float* __restrict__ zz0,
    const float* __restrict__ rot1, const float* __restrict__ zz1,
    const float* __restrict__ Wo, const float* __restrict__ bo,
    float* __restrict__ out)
{
  const int b = blockIdx.x, tid = threadIdx.x;
  const int lane = tid & 63, wv = tid >> 6;

  __shared__ float thp[48][4];
  __shared__ C vq[16][2];
  __shared__ C M0s[16][4];
  __shared__ C M1s[8][4];
  __shared__ C lam[2];
  __shared__ C zp0h[7][2], zp0l[7][2];   // e^{-i th/2} (equal), e^{+i th/2} (diff)
  __shared__ float zz1s[7];
  __shared__ C W[4][256];                // A0, A1, B0, B1
  __shared__ float GH00[16], GH11[16], GL00[16], GL11[16];
  __shared__ C GH01[16], GL01[16];
  __shared__ float w[256];
  __shared__ float part[4];
  __shared__ C Mx[2][16][16];
  __shared__ C s8[256];

  // ---- prefetch head weights (used only at the very end, wave 0) ----
  float4 wo4 = make_float4(0.f,0.f,0.f,0.f); float bor = 0.f;
  if (tid < 64){ wo4 = ((const float4*)Wo)[tid]; bor = bo[tid]; }

  // ---- prep: angle GEMM partials (tid<192) + gate matrices / tables (tid>=192) ----
  if (tid < 192){
    int o = tid>>2, prt = tid&3;
    int g = o/12, j = o - g*12;
    const float* f = (g==0) ? (slf + (size_t)b*128) : (nbr + ((size_t)b*3 + (g-1))*128);
    const float4* f4 = (const float4*)(f + prt*32);
    const float4* w4 = (const float4*)(Wp + j*128 + prt*32);
    float acc = 0.f;
    #pragma unroll
    for (int d=0; d<8; d++){
      float4 a = f4[d], c = w4[d];
      acc += a.x*c.x + a.y*c.y + a.z*c.z + a.w*c.w;
    }
    thp[o][prt] = acc;
  } else if (tid < 208){
    int q = tid-192;
    fused_M(rot0[q*3+0], rot0[q*3+1], rot0[q*3+2], &M0s[q][0]);
  } else if (tid < 216){
    int q = tid-208;
    fused_M(rot1[q*3+0], rot1[q*3+1], rot1[q*3+2], &M1s[q][0]);
  } else if (tid < 223){
    zz1s[tid-216] = zz1[tid-216];
  } else if (tid == 223){
    // boundary ZZ pair rank-2 split: [[a,b],[b,a]] = c*(1x1) + (-i s)*(sgn x sgn)
    float s,c; sincosf(0.5f*zz0[7],&s,&c);
    lam[0] = C{c,0.f}; lam[1] = C{0.f,-s};
  } else if (tid < 231){
    int k = tid-224;
    float s,c; sincosf(0.5f*zz0[k],&s,&c);
    zp0h[k][0] = C{c,-s}; zp0h[k][1] = C{c, s};
  } else if (tid < 238){
    int k = tid-231;
    float s,c; sincosf(0.5f*zz0[8+k],&s,&c);
    zp0l[k][0] = C{c,-s}; zp0l[k][1] = C{c, s};
  }
  __syncthreads();                                        // B1
  if (tid < 16){
    // angles for qubit tid: o = 3*tid + c, j = o % 12
    float ang[3];
    #pragma unroll
    for (int c=0;c<3;c++){
      int o = tid*3 + c;
      ang[c] = thp[o][0]+thp[o][1]+thp[o][2]+thp[o][3] + bp[o%12];
    }
    C M[4]; fused_M(ang[0], ang[1], ang[2], M);
    vq[tid][0] = M[0]; vq[tid][1] = M[1];   // row 0 of e0^T * RxRyRz (encoding on |0>)
  }
  __syncthreads();                                        // B2

  // ---- W-init in registers: wave wv owns array wv; 4 amps/lane, h=(lane<<2)|r ----
  C a[4];
  #pragma unroll
  for (int r=0;r<4;++r){
    int h = (lane<<2) | r;
    C V;
    if (wv < 2){
      V = vq[0][(h>>7)&1];
      #pragma unroll
      for (int q=1;q<8;q++) V = cmul(V, vq[q][(h>>(7-q))&1]);
      #pragma unroll
      for (int kk=0;kk<7;kk++){
        int b0=(h>>(7-kk))&1, b1=(h>>(6-kk))&1;
        V = cmul(V, zp0h[kk][(b0^b1)]);
      }
      if (wv == 0){
        V = cmul(V, lam[0]);
      } else {
        V = cmul(V, lam[1]);
        if (h & 1){ V.x = -V.x; V.y = -V.y; }
      }
    } else {
      V = vq[8][(h>>7)&1];
      #pragma unroll
      for (int q=9;q<16;q++) V = cmul(V, vq[q][(h>>(15-q))&1]);
      #pragma unroll
      for (int kk=8;kk<15;kk++){
        int b0=(h>>(15-kk))&1, b1=(h>>(14-kk))&1;
        V = cmul(V, zp0l[kk-8][(b0^b1)]);
      }
      if (wv == 3 && ((h>>7)&1)){ V.x = -V.x; V.y = -V.y; }
    }
    a[r] = V;
  }

  // ---- conv0: 8 levels in registers (bits 0,1 in-slot; bits 2..7 via shfl_xor) ----
  // h bit pb <-> qubit 7-pb (A side: M0s[7-pb]) / qubit 15-pb (B side: M0s[15-pb])
  #pragma unroll
  for (int pb=0; pb<8; ++pb){
    const C* G = (wv < 2) ? &M0s[7-pb][0] : &M0s[15-pb][0];
    if (pb == 0){
      bfly(a[0],a[1],G); bfly(a[2],a[3],G);
    } else if (pb == 1){
      bfly(a[0],a[2],G); bfly(a[1],a[3],G);
    } else {
      int msk = 1<<(pb-2);
      int bbit = (lane>>(pb-2))&1;
      C gd = bbit ? G[3] : G[0];
      C go = bbit ? G[1] : G[2];
      #pragma unroll
      for (int r=0;r<4;++r){
        C oth{ __shfl_xor(a[r].x, msk), __shfl_xor(a[r].y, msk) };
        C t0 = cmul(a[r], gd), t1 = cmul(oth, go);
        a[r] = C{t0.x+t1.x, t0.y+t1.y};
      }
    }
  }
  #pragma unroll
  for (int r=0;r<4;++r) W[wv][(lane<<2)|r] = a[r];
  __syncthreads();                                        // B3

  // ---- Gram vectors (lanes 0..31 of wave 0) [verified r4] ----
  if (tid < 32){
    int side = tid>>4, tq = tid&15;
    float g00=0.f, g11=0.f; C g01{0.f,0.f};
    #pragma unroll
    for (int kq=0;kq<16;kq++){
      int idx = expand44(tq,kq);
      C a0 = W[side*2+0][idx], a1 = W[side*2+1][idx];
      g00 += a0.x*a0.x + a0.y*a0.y;
      g11 += a1.x*a1.x + a1.y*a1.y;
      g01.x += a0.x*a1.x + a0.y*a1.y;
      g01.y += a0.y*a1.x - a0.x*a1.y;
    }
    if (side==0){ GH00[tq]=g00; GH11[tq]=g11; GH01[tq]=g01; }
    else        { GL00[tq]=g00; GL11[tq]=g11; GL01[tq]=g01; }
  }
  __syncthreads();                                        // B4

  // ---- p(t), wave-shuffle total, weights [verified r4] ----
  float pv;
  {
    int tH = tid>>4, tL = tid&15;
    C gh = GH01[tH], gl = GL01[tL];
    pv = GH00[tH]*GL00[tL] + GH11[tH]*GL11[tL] + 2.f*(gh.x*gl.x - gh.y*gl.y);
    pv = fmaxf(pv, 0.f);
  }
  {
    float v = pv;
    #pragma unroll
    for (int off=32; off>0; off>>=1) v += __shfl_down(v, off);
    if (lane==0) part[wv] = v;
  }
  __syncthreads();                                        // B5
  {
    float tot = part[0]+part[1]+part[2]+part[3];
    w[tid] = sqrtf(pv/(tot + 1e-10f));
  }
  __syncthreads();                                        // B6

  // ---- Mx[r][tH][kL] = sum_tL w(tH,tL) * B_r(tL,kL) [verified r4] ----
  #pragma unroll
  for (int rep=0; rep<2; ++rep){
    int e = tid + rep*256;
    int r = e>>8, tH = (e>>4)&15, kL = e&15;
    C acc{0.f,0.f};
    #pragma unroll
    for (int tL=0;tL<16;tL++){
      float ww = w[(tH<<4)|tL];
      C bv = W[2+r][expand44(tL,kL)];
      acc.x += ww*bv.x; acc.y += ww*bv.y;
    }
    Mx[r][tH][kL] = acc;
  }
  __syncthreads();                                        // B7

  // ---- s1(k), norm via shuffle reduce, conv1 ZZ diag [verified r4] ----
  C s1{0.f,0.f};
  {
    int kH = tid>>4, kL = tid&15;
    #pragma unroll
    for (int tH=0;tH<16;tH++){
      int ia = expand44(tH,kH);
      C a0 = W[0][ia], m0 = Mx[0][tH][kL];
      C a1 = W[1][ia], m1 = Mx[1][tH][kL];
      s1.x += a0.x*m0.x - a0.y*m0.y + a1.x*m1.x - a1.y*m1.y;
      s1.y += a0.x*m0.y + a0.y*m0.x + a1.x*m1.y + a1.y*m1.x;
    }
  }
  {
    float v = s1.x*s1.x + s1.y*s1.y;
    #pragma unroll
    for (int off=32; off>0; off>>=1) v += __shfl_down(v, off);
    if (lane==0) part[wv] = v;
  }
  __syncthreads();                                        // B8
  {
    float n1 = sqrtf(part[0]+part[1]+part[2]+part[3] + 1e-10f);
    float A = 0.f;
    #pragma unroll
    for (int kk=0;kk<7;kk++){
      int b0=(tid>>(7-kk))&1, b1=(tid>>(6-kk))&1;
      A += (b0==b1) ? zz1s[kk] : -zz1s[kk];
    }
    float sa,ca; sincosf(0.5f*A,&sa,&ca);
    C s1n{s1.x/n1, s1.y/n1};
    s8[tid] = cmul(s1n, C{ca,-sa});
  }
  __syncthreads();                                        // B9

  // ---- wave 0: conv1 + pool2 + measure + head, all in registers ----
  if (wv == 0){
    C c4[4];
    #pragma unroll
    for (int r=0;r<4;++r) c4[r] = s8[(lane<<2)|r];
    // conv1: k bit pb <-> qubit 7-pb -> M1s[7-pb]
    #pragma unroll
    for (int pb=0; pb<8; ++pb){
      const C* G = &M1s[7-pb][0];
      if (pb == 0){
        bfly(c4[0],c4[1],G); bfly(c4[2],c4[3],G);
      } else if (pb == 1){
        bfly(c4[0],c4[2],G); bfly(c4[1],c4[3],G);
      } else {
        int msk = 1<<(pb-2);
        int bbit = (lane>>(pb-2))&1;
        C gd = bbit ? G[3] : G[0];
        C go = bbit ? G[1] : G[2];
        #pragma unroll
        for (int r=0;r<4;++r){
          C oth{ __shfl_xor(c4[r].x, msk), __shfl_xor(c4[r].y, msk) };
          C t0 = cmul(c4[r], gd), t1 = cmul(oth, go);
          c4[r] = C{t0.x+t1.x, t0.y+t1.y};
        }
      }
    }
    // pool2: j=(lane<<2)|r; t2 = (r&1, l0,l2,l4), k2 = (r>>1, l1,l3,l5)
    float q0 = c4[0].x*c4[0].x + c4[0].y*c4[0].y + c4[2].x*c4[2].x + c4[2].y*c4[2].y;
    float q1 = c4[1].x*c4[1].x + c4[1].y*c4[1].y + c4[3].x*c4[3].x + c4[3].y*c4[3].y;
    q0 += __shfl_xor(q0, 2);  q1 += __shfl_xor(q1, 2);
    q0 += __shfl_xor(q0, 8);  q1 += __shfl_xor(q1, 8);
    q0 += __shfl_xor(q0, 32); q1 += __shfl_xor(q1, 32);
    float S2 = q0 + q1;
    S2 += __shfl_xor(S2, 1); S2 += __shfl_xor(S2, 4); S2 += __shfl_xor(S2, 16);
    float w20 = sqrtf(q0/(S2 + 1e-10f));
    float w21 = sqrtf(q1/(S2 + 1e-10f));
    // s2(k2): u0 = k2b0=0, u1 = k2b0=1; sum over t2 (lane bits 0,2,4)
    C u0{ c4[0].x*w20 + c4[1].x*w21, c4[0].y*w20 + c4[1].y*w21 };
    C u1{ c4[2].x*w20 + c4[3].x*w21, c4[2].y*w20 + c4[3].y*w21 };
    #pragma unroll
    for (int m=0;m<3;m++){
      int msk = 1<<(2*m);     // 1,4,16
      u0.x += __shfl_xor(u0.x, msk); u0.y += __shfl_xor(u0.y, msk);
      u1.x += __shfl_xor(u1.x, msk); u1.y += __shfl_xor(u1.y, msk);
    }
    float nn = u0.x*u0.x + u0.y*u0.y + u1.x*u1.x + u1.y*u1.y;
    nn += __shfl_xor(nn, 2); nn += __shfl_xor(nn, 8); nn += __shfl_xor(nn, 32);
    nn += 1e-10f;
    float p0 = (u0.x*u0.x + u0.y*u0.y)/nn;
    float p1 = (u1.x*u1.x + u1.y*u1.y)/nn;
    // measure_z: qubit q <-> k2 bit 3-q. k2 bits: b0=slot, b1=l1, b2=l3, b3=l5
    float base = p0 + p1;
    float z3 = p0 - p1;
    float z2 = ((lane>>1)&1) ? -base : base;
    float z1 = ((lane>>3)&1) ? -base : base;
    float z0 = ((lane>>5)&1) ? -base : base;
    #pragma unroll
    for (int m=0;m<3;m++){
      int msk = 2<<(2*m);     // 2,8,32
      z0 += __shfl_xor(z0, msk); z1 += __shfl_xor(z1, msk);
      z2 += __shfl_xor(z2, msk); z3 += __shfl_xor(z3, msk);
    }
    float r = bor + z0*wo4.x + z1*wo4.y + z2*wo4.z + z3*wo4.w;
    out[(size_t)b*64 + lane] = r;
  }
}

extern "C" void kernel_launch(void* const* d_in, const int* in_sizes, int n_in,
                              void* d_out, int out_size, void* d_ws, size_t ws_size,
                              hipStream_t stream) {
  const float* nbr  = (const float*)d_in[0];
  const float* slf  = (const float*)d_in[1];
  const float* Wp   = (const float*)d_in[2];
  const float* bp   = (const float*)d_in[3];
  const float* rot0 = (const float*)d_in[4];
  const float* zz0  = (const float*)d_in[5];
  const float* rot1 = (const float*)d_in[6];
  const float* zz1  = (const float*)d_in[7];
  const float* Wo   = (const float*)d_in[8];
  const float* bo   = (const float*)d_in[9];
  float* out = (float*)d_out;

  hipLaunchKernelGGL(k_all, dim3(NB), dim3(256), 0, stream,
                     nbr, slf, Wp, bp, rot0, zz0, rot1, zz1, Wo, bo, out);
}

// Round 7
// 17.423 us; speedup vs baseline: 1.3981x; 1.0523x over previous
//
#include <hip/hip_runtime.h>
#include <math.h>

#define NB 64

struct C { float x, y; };

__device__ __forceinline__ C cmul(C a, C b){ return C{a.x*b.x - a.y*b.y, a.x*b.y + a.y*b.x}; }

// new_j = sum_i x_i * G[i][j]  (reference einsum contracts gate's FIRST index with state)
__device__ __forceinline__ void bfly(C& x0, C& x1, const C* G){
  C n0 = C{x0.x*G[0].x - x0.y*G[0].y + x1.x*G[2].x - x1.y*G[2].y,
           x0.x*G[0].y + x0.y*G[0].x + x1.x*G[2].y + x1.y*G[2].x};
  C n1 = C{x0.x*G[1].x - x0.y*G[1].y + x1.x*G[3].x - x1.y*G[3].y,
           x0.x*G[1].y + x0.y*G[1].x + x1.x*G[3].y + x1.y*G[3].x};
  x0 = n0; x1 = n1;
}

// interleave: t2 bits -> even positions, k2 bits -> odd positions
__device__ __forceinline__ int expand44(int t2, int k2){
  int j=0;
  #pragma unroll
  for (int m=0;m<4;m++){ j |= ((t2>>m)&1)<<(2*m); j |= ((k2>>m)&1)<<(2*m+1); }
  return j;
}

// M = Rx(tx)*Ry(ty)*Rz(tz), row-major M[i*2+j]; reference applies new = x^T * M
__device__ void fused_M(float tx, float ty, float tz, C* M){
  float cx=cosf(0.5f*tx), sx=sinf(0.5f*tx);
  float cy=cosf(0.5f*ty), sy=sinf(0.5f*ty);
  float cz=cosf(0.5f*tz), sz=sinf(0.5f*tz);
  C b0 = C{ cx*cy, -sx*sy};
  C b1 = C{-cx*sy, -sx*cy};
  C b2 = C{ cx*sy, -sx*cy};
  C b3 = C{ cx*cy,  sx*sy};
  C e0 = C{cz,-sz}, e1 = C{cz, sz};
  M[0]=cmul(b0,e0); M[1]=cmul(b1,e1);
  M[2]=cmul(b2,e0); M[3]=cmul(b3,e1);
}

// ================= SINGLE KERNEL: rank-2 factored simulation, low-barrier =================
__global__ __launch_bounds__(256) void k_all(
    const float* __restrict__ nbr, const float* __restrict__ slf,
    const float* __restrict__ Wp, const float* __restrict__ bp,
    const float* __restrict__ rot0, const float* __restrict__ zz0,
    const float* __restrict__ rot1, const float* __restrict__ zz1,
    const float* __restrict__ Wo, const float* __restrict__ bo,
    float* __restrict__ out)
{
  const int b = blockIdx.x, tid = threadIdx.x;

  __shared__ float thp[48][4];
  __shared__ float th[48];
  __shared__ C vq[16][2];
  __shared__ float zz0s[15];
  __shared__ C M0s[16][4];
  __shared__ C lam[2];
  __shared__ C W[4][256];               // A0, A1, B0, B1
  __shared__ float GH00[16], GH11[16], GL00[16], GL11[16];
  __shared__ C GH01[16], GL01[16];
  __shared__ float w[256];
  __shared__ float part[4];
  __shared__ C Mx[2][16][16];
  __shared__ C s8[256];
  __shared__ C M1s[8][4];
  __shared__ float zz1s[7];

  // ---- prefetch head weights into registers (used only at the very end) ----
  float4 wo4 = make_float4(0.f,0.f,0.f,0.f); float bor = 0.f;
  if (tid < 64){ wo4 = ((const float4*)Wo)[tid]; bor = bo[tid]; }

  // ---- parallel prep: angle GEMM partials (tid<192) + gate matrices (tid>=192) ----
  if (tid < 15) zz0s[tid] = zz0[tid];
  if (tid < 192){
    int o = tid>>2, prt = tid&3;
    int g = o/12, j = o - g*12;
    const float* f = (g==0) ? (slf + (size_t)b*128) : (nbr + ((size_t)b*3 + (g-1))*128);
    const float4* f4 = (const float4*)(f + prt*32);
    const float4* w4 = (const float4*)(Wp + j*128 + prt*32);
    float acc = 0.f;
    #pragma unroll
    for (int d=0; d<8; d++){
      float4 a = f4[d], c = w4[d];
      acc += a.x*c.x + a.y*c.y + a.z*c.z + a.w*c.w;
    }
    thp[o][prt] = acc;
  } else if (tid < 208){
    int q = tid-192;
    fused_M(rot0[q*3+0], rot0[q*3+1], rot0[q*3+2], &M0s[q][0]);
  } else if (tid < 216){
    int q = tid-208;
    fused_M(rot1[q*3+0], rot1[q*3+1], rot1[q*3+2], &M1s[q][0]);
  } else if (tid < 223){
    zz1s[tid-216] = zz1[tid-216];
  } else if (tid == 223){
    // boundary ZZ pair rank-2 split: [[a,b],[b,a]] = c*(1x1) + (-i s)*(sgn x sgn)
    float s,c; sincosf(0.5f*zz0[7],&s,&c);
    lam[0] = C{c,0.f}; lam[1] = C{0.f,-s};
  }
  __syncthreads();                                        // B1
  if (tid < 48) th[tid] = thp[tid][0]+thp[tid][1]+thp[tid][2]+thp[tid][3] + bp[tid%12];
  __syncthreads();                                        // B2
  if (tid < 16){
    C M[4]; fused_M(th[tid*3+0], th[tid*3+1], th[tid*3+2], M);
    vq[tid][0] = M[0]; vq[tid][1] = M[1];   // row 0 of e0^T * RxRyRz (encoding on |0>)
  }
  __syncthreads();                                        // B3

  // ---- byte-function init: Vh/Vl -> A0,A1,B0,B1 (verified) ----
  {
    int h = tid;
    C p = vq[0][(h>>7)&1];
    #pragma unroll
    for (int q=1;q<8;q++) p = cmul(p, vq[q][(h>>(7-q))&1]);
    float A = 0.f;
    #pragma unroll
    for (int kk=0;kk<7;kk++){
      int b0=(h>>(7-kk))&1, b1=(h>>(6-kk))&1;
      A += (b0==b1) ? zz0s[kk] : -zz0s[kk];
    }
    float s,c; sincosf(0.5f*A,&s,&c);
    C Vh = cmul(p, C{c,-s});
    C pl = vq[8][(h>>7)&1];
    #pragma unroll
    for (int q=9;q<16;q++) pl = cmul(pl, vq[q][(h>>(15-q))&1]);
    float Al = 0.f;
    #pragma unroll
    for (int kk=8;kk<15;kk++){
      int b0=(h>>(15-kk))&1, b1=(h>>(14-kk))&1;
      Al += (b0==b1) ? zz0s[kk] : -zz0s[kk];
    }
    sincosf(0.5f*Al,&s,&c);
    C Vl = cmul(pl, C{c,-s});
    W[0][h] = cmul(Vh, lam[0]);
    C a1 = cmul(Vh, lam[1]);
    if (h & 1){ a1.x = -a1.x; a1.y = -a1.y; }
    W[1][h] = a1;
    W[2][h] = Vl;
    W[3][h] = ((h>>7)&1) ? C{-Vl.x,-Vl.y} : Vl;
  }
  __syncthreads();                                        // B4

  // ---- conv0 rotations: 8 butterfly levels, 2 per barrier ----
  // h bit pb <-> qubit 7-pb (M0s[7-pb]); l bit pb <-> qubit 15-pb (M0s[15-pb])
  #pragma unroll
  for (int p=0; p<8; p+=2){
    int arr = tid>>6, i = tid&63;
    const C* Glo = (arr<2) ? &M0s[7-p][0]  : &M0s[15-p][0];
    const C* Ghi = (arr<2) ? &M0s[6-p][0]  : &M0s[14-p][0];
    int mp = 1<<p;
    int x = ((i>>p)<<(p+2)) | (i & (mp-1));
    C c0 = W[arr][x], c1 = W[arr][x|mp], c2 = W[arr][x|(mp<<1)], c3 = W[arr][x|mp|(mp<<1)];
    bfly(c0,c1,Glo); bfly(c2,c3,Glo);
    bfly(c0,c2,Ghi); bfly(c1,c3,Ghi);
    W[arr][x]=c0; W[arr][x|mp]=c1; W[arr][x|(mp<<1)]=c2; W[arr][x|mp|(mp<<1)]=c3;
    __syncthreads();                                      // B5..B8
  }

  // ---- Gram vectors ----
  if (tid < 32){
    int side = tid>>4, tq = tid&15;
    float g00=0.f, g11=0.f; C g01{0.f,0.f};
    #pragma unroll
    for (int kq=0;kq<16;kq++){
      int idx = expand44(tq,kq);
      C a0 = W[side*2+0][idx], a1 = W[side*2+1][idx];
      g00 += a0.x*a0.x + a0.y*a0.y;
      g11 += a1.x*a1.x + a1.y*a1.y;
      g01.x += a0.x*a1.x + a0.y*a1.y;
      g01.y += a0.y*a1.x - a0.x*a1.y;
    }
    if (side==0){ GH00[tq]=g00; GH11[tq]=g11; GH01[tq]=g01; }
    else        { GL00[tq]=g00; GL11[tq]=g11; GL01[tq]=g01; }
  }
  __syncthreads();                                        // B9

  // ---- p(t), total via wave-shuffle reduce, weights ----
  float pv;
  {
    int tH = tid>>4, tL = tid&15;
    C gh = GH01[tH], gl = GL01[tL];
    pv = GH00[tH]*GL00[tL] + GH11[tH]*GL11[tL] + 2.f*(gh.x*gl.x - gh.y*gl.y);
    pv = fmaxf(pv, 0.f);
  }
  {
    float v = pv;
    #pragma unroll
    for (int off=32; off>0; off>>=1) v += __shfl_down(v, off);
    if ((tid&63)==0) part[tid>>6] = v;
  }
  __syncthreads();                                        // B10
  {
    float tot = part[0]+part[1]+part[2]+part[3];
    w[tid] = sqrtf(pv/(tot + 1e-10f));
  }
  __syncthreads();                                        // B11

  // ---- Mx[r][tH][kL] = sum_tL w(tH,tL) * B_r(tL,kL) ----
  #pragma unroll
  for (int rep=0; rep<2; ++rep){
    int e = tid + rep*256;
    int r = e>>8, tH = (e>>4)&15, kL = e&15;
    C acc{0.f,0.f};
    #pragma unroll
    for (int tL=0;tL<16;tL++){
      float ww = w[(tH<<4)|tL];
      C bv = W[2+r][expand44(tL,kL)];
      acc.x += ww*bv.x; acc.y += ww*bv.y;
    }
    Mx[r][tH][kL] = acc;
  }
  __syncthreads();                                        // B12

  // ---- s1(k), norm via shuffle reduce ----
  C s1{0.f,0.f};
  {
    int kH = tid>>4, kL = tid&15;
    #pragma unroll
    for (int tH=0;tH<16;tH++){
      int ia = expand44(tH,kH);
      C a0 = W[0][ia], m0 = Mx[0][tH][kL];
      C a1 = W[1][ia], m1 = Mx[1][tH][kL];
      s1.x += a0.x*m0.x - a0.y*m0.y + a1.x*m1.x - a1.y*m1.y;
      s1.y += a0.x*m0.y + a0.y*m0.x + a1.x*m1.y + a1.y*m1.x;
    }
  }
  {
    float v = s1.x*s1.x + s1.y*s1.y;
    #pragma unroll
    for (int off=32; off>0; off>>=1) v += __shfl_down(v, off);
    if ((tid&63)==0) part[tid>>6] = v;
  }
  __syncthreads();                                        // B13
  {
    float n1 = sqrtf(part[0]+part[1]+part[2]+part[3] + 1e-10f);
    s1.x /= n1; s1.y /= n1;
  }
  // conv1 ZZ diagonal + store s8
  {
    float A = 0.f;
    #pragma unroll
    for (int kk=0;kk<7;kk++){
      int b0=(tid>>(7-kk))&1, b1=(tid>>(6-kk))&1;
      A += (b0==b1) ? zz1s[kk] : -zz1s[kk];
    }
    float sa,ca; sincosf(0.5f*A,&sa,&ca);
    s8[tid] = cmul(s1, C{ca,-sa});
  }
  __syncthreads();                                        // B14

  // ---- conv1: 8 levels, 2 per barrier (threads 0..63 active) ----
  // level q applies M1s[q] on bit 7-q; pair j handles (q=2j bit hb, q=2j+1 bit lb)
  #pragma unroll
  for (int j=0; j<4; ++j){
    if (tid < 64){
      int hb = 7-2*j, lb = 6-2*j;
      int ml = 1<<lb, mh = 1<<hb;
      int x = ((tid>>lb)<<(lb+1)) | (tid & (ml-1));
      x = ((x>>hb)<<(hb+1)) | (x & (mh-1));
      C c0 = s8[x], c1 = s8[x|mh], c2 = s8[x|ml], c3 = s8[x|mh|ml];
      bfly(c0,c1,&M1s[2*j][0]);   bfly(c2,c3,&M1s[2*j][0]);
      bfly(c0,c2,&M1s[2*j+1][0]); bfly(c1,c3,&M1s[2*j+1][0]);
      s8[x]=c0; s8[x|mh]=c1; s8[x|ml]=c2; s8[x|mh|ml]=c3;
    }
    __syncthreads();                                      // B15..B18
  }

  // ---- barrier-free tail in wave 0 (pool2 + measure + head), registers + shuffles ----
  if (tid < 64){
    int ld = tid & 15;
    // p2
    float p2v = 0.f;
    #pragma unroll
    for (int k2=0;k2<16;k2++){ C v=s8[expand44(ld,k2)]; p2v += v.x*v.x + v.y*v.y; }
    float S2 = p2v;
    #pragma unroll
    for (int off=1; off<16; off<<=1) S2 += __shfl_xor(S2, off);   // sum within 16-lane group
    float w2 = sqrtf(p2v/(S2 + 1e-10f));
    // s2
    C a2{0.f,0.f};
    #pragma unroll
    for (int t2=0;t2<16;t2++){
      float ww = __shfl(w2, t2);          // lanes 0..15 hold valid w2
      C v = s8[expand44(t2, ld)];
      a2.x += v.x*ww; a2.y += v.y*ww;
    }
    float nn = a2.x*a2.x + a2.y*a2.y;
    #pragma unroll
    for (int off=1; off<16; off<<=1) nn += __shfl_xor(nn, off);
    nn += 1e-10f;
    float pr = (a2.x*a2.x + a2.y*a2.y)/nn;   // lane ld represents idx=ld
    // measure_z: zm[q] = sum_idx sign(idx,q)*pr_idx  (qubit q <-> bit 3-q)
    float z0=0.f,z1=0.f,z2=0.f,z3=0.f;
    #pragma unroll
    for (int idx=0; idx<16; idx++){
      float p_ = __shfl(pr, idx);
      z0 += ((idx>>3)&1) ? -p_ : p_;
      z1 += ((idx>>2)&1) ? -p_ : p_;
      z2 += ((idx>>1)&1) ? -p_ : p_;
      z3 += ( idx     &1) ? -p_ : p_;
    }
    // head
    float r = bor + z0*wo4.x + z1*wo4.y + z2*wo4.z + z3*wo4.w;
    out[(size_t)b*64 + tid] = r;
  }
}

extern "C" void kernel_launch(void* const* d_in, const int* in_sizes, int n_in,
                              void* d_out, int out_size, void* d_ws, size_t ws_size,
                              hipStream_t stream) {
  const float* nbr  = (const float*)d_in[0];
  const float* slf  = (const float*)d_in[1];
  const float* Wp   = (const float*)d_in[2];
  const float* bp   = (const float*)d_in[3];
  const float* rot0 = (const float*)d_in[4];
  const float* zz0  = (const float*)d_in[5];
  const float* rot1 = (const float*)d_in[6];
  const float* zz1  = (const float*)d_in[7];
  const float* Wo   = (const float*)d_in[8];
  const float* bo   = (const float*)d_in[9];
  float* out = (float*)d_out;

  hipLaunchKernelGGL(k_all, dim3(NB), dim3(256), 0, stream,
                     nbr, slf, Wp, bp, rot0, zz0, rot1, zz1, Wo, bo, out);
}